// Round 3
// baseline (485.319 us; speedup 1.0000x reference)
//
#include <hip/hip_runtime.h>
#include <cstdint>

// Fused Bayesian LSTM: B=4096, T=200, IN=79, H=10 (gates G=40)
// ws layout (floats): [0,3160) Wih_hat, [3160,3560) Whh_hat, [3560,3600) bias_hat
#define Bsz 4096
#define Tlen 200
#define INs 79
#define Hs 10
#define Gs 40

__global__ void prep_kernel(const float* __restrict__ wih_mu, const float* __restrict__ wih_rho, const float* __restrict__ wih_eps,
                            const float* __restrict__ whh_mu, const float* __restrict__ whh_rho, const float* __restrict__ whh_eps,
                            const float* __restrict__ b_mu,   const float* __restrict__ b_rho,   const float* __restrict__ b_eps,
                            float* __restrict__ w) {
    int i = blockIdx.x * 256 + threadIdx.x;
    if (i >= 3600) return;
    const float *mu, *rho, *eps; int k;
    if (i < 3160)      { mu = wih_mu; rho = wih_rho; eps = wih_eps; k = i; }
    else if (i < 3560) { mu = whh_mu; rho = whh_rho; eps = whh_eps; k = i - 3160; }
    else               { mu = b_mu;   rho = b_rho;   eps = b_eps;   k = i - 3560; }
    float r = rho[k];
    float sp = (r > 20.0f) ? r : log1pf(expf(r));   // softplus, stable
    w[i] = fmaf(sp, eps[k], mu[k]);
}

// One wave (64-thread block) per batch row. b = blockIdx.x => the x-row
// pointer is provably uniform => the 79 x values per timestep become
// s_load_dwordx16 (SGPR broadcast operand in v_fmac). Lane j<40 owns gate
// (u=j>>2, ty=j&3); ty: 0=i, 1=f, 2=g, 3=o (quad-interleaved so i/f/g/o
// combine via 3 DPP quad_perms). h broadcast back via readlane -> SGPR.
// An async global_load_lds prefetch (never read, no waitcnt) warms L2 so
// the per-t scalar loads don't stall on HBM (~900cy).
__global__ __launch_bounds__(64, 4) void fused_kernel(
    const float* __restrict__ x, const float* __restrict__ w,
    const float* __restrict__ lin_w, const float* __restrict__ lin_b,
    float* __restrict__ out) {
    __shared__ float scratch[64];                 // prefetch sink, never read
    const int b = blockIdx.x;
    const int j = threadIdx.x;                    // lane
    int pj = (j & 3) * 10 + (j >> 2); pj = pj > 39 ? 39 : pj;  // gate column; clamp lanes >39

    float wv[INs];                                // Wih column for this gate (VGPRs)
#pragma unroll
    for (int i = 0; i < INs; ++i) wv[i] = w[i * Gs + pj];
    float wc[Hs];                                 // Whh column
#pragma unroll
    for (int k = 0; k < Hs; ++k) wc[k] = w[3160 + k * Gs + pj];
    const float bv = w[3560 + pj];                // bias

    const int ty = j & 3;
    const float sA = (ty == 2) ? -2.0f : -1.0f;   // exp(-x) vs exp(-2x)
    const float sM = (ty == 2) ?  2.0f :  1.0f;   // tanh = 2*sigmoid(2x)-1
    const float sC = (ty == 2) ? -1.0f :  0.0f;

    float hs[Hs];
#pragma unroll
    for (int k = 0; k < Hs; ++k) hs[k] = 0.0f;
    float c = 0.0f;

    const float* xb = x + (long)b * Tlen * INs;   // uniform
    const long xlast = (long)Bsz * Tlen * INs - 128;  // clamp so prefetch stays in-bounds
    auto* lds_sink = (__attribute__((address_space(3))) float*)scratch;

    for (int t = 0; t < Tlen; ++t) {
        // ---- async L2-warm prefetch of row t+4 (results never read) ----
        {
            int tp = t + 4; tp = tp < Tlen ? tp : Tlen - 1;
            long off = (long)b * Tlen * INs + (long)tp * INs;
            if (off > xlast) off = xlast;
            auto* g = (const __attribute__((address_space(1))) float*)(x + off) + j;
            __builtin_amdgcn_global_load_lds(g, lds_sink, 4, 0, 0);
            __builtin_amdgcn_global_load_lds(g + 64, lds_sink, 4, 0, 0);
        }
        // ---- input projection: 79 scalar x values (SGPR) * per-lane Wih col ----
        const float* xr = xb + (long)t * INs;     // uniform -> s_load
        float a0 = bv, a1 = 0.0f;
#pragma unroll
        for (int i = 0; i < INs - 1; i += 2) {
            a0 = fmaf(xr[i],     wv[i],     a0);
            a1 = fmaf(xr[i + 1], wv[i + 1], a1);
        }
        a0 = fmaf(xr[INs - 1], wv[INs - 1], a0);  // i=78
        float acc = a0 + a1;
        // ---- recurrent term: h (SGPR broadcast) * Whh col ----
#pragma unroll
        for (int k = 0; k < Hs; ++k) acc = fmaf(hs[k], wc[k], acc);
        // ---- activations (sigmoid for i,f,o; tanh for g) ----
        float e  = __expf(acc * sA);
        float sg = __builtin_amdgcn_rcpf(1.0f + e);
        float act = fmaf(sg, sM, sC);
        int ai = __float_as_int(act);
        float a1d = __int_as_float(__builtin_amdgcn_mov_dpp(ai, 0xB1, 0xF, 0xF, true)); // quad xor1
        float a2d = __int_as_float(__builtin_amdgcn_mov_dpp(ai, 0x4E, 0xF, 0xF, true)); // quad xor2
        float a3d = __int_as_float(__builtin_amdgcn_mov_dpp(ai, 0x1B, 0xF, 0xF, true)); // quad xor3
        // valid in ty==0 lanes: act=i, a1d=f, a2d=g, a3d=o
        c = fmaf(a1d, c, act * a2d);              // c = f*c + i*g
        float e2 = __expf(-2.0f * c);
        float th = fmaf(2.0f, __builtin_amdgcn_rcpf(1.0f + e2), -1.0f);  // tanh(c)
        float hn = a3d * th;                      // h = o * tanh(c)
#pragma unroll
        for (int k = 0; k < Hs; ++k)
            hs[k] = __int_as_float(__builtin_amdgcn_readlane(__float_as_int(hn), 4 * k));
    }
    if (j == 0) {
        float o = lin_b[0];
#pragma unroll
        for (int k = 0; k < Hs; ++k) o = fmaf(hs[k], lin_w[k], o);
        out[b] = o;
    }
}

extern "C" void kernel_launch(void* const* d_in, const int* in_sizes, int n_in,
                              void* d_out, int out_size, void* d_ws, size_t ws_size,
                              hipStream_t stream) {
    const float* x = (const float*)d_in[0];
    float* w   = (float*)d_ws;
    float* out = (float*)d_out;

    prep_kernel<<<15, 256, 0, stream>>>(
        (const float*)d_in[1], (const float*)d_in[2], (const float*)d_in[3],
        (const float*)d_in[4], (const float*)d_in[5], (const float*)d_in[6],
        (const float*)d_in[7], (const float*)d_in[8], (const float*)d_in[9], w);

    fused_kernel<<<Bsz, 64, 0, stream>>>(
        x, w, (const float*)d_in[10], (const float*)d_in[11], out);
}

// Round 4
// 252.191 us; speedup vs baseline: 1.9244x; 1.9244x over previous
//
#include <hip/hip_runtime.h>
#include <cstdint>

// Bayesian LSTM: B=4096, T=200, IN=79, H=10 (gates G=40)
// ws float layout:
//  [0,3160)    Wih_hat split by gate-type: part ty in {0..3} at ty*790 + i*10 + u
//              == Wih_hat[i][ty*10+u]   (ty*10+u = gate column c)
//  [3160,3560) Whh_hat natural: 3160 + k*40 + c
//  [3560,3600) bias_hat natural: 3560 + c
//  [4096,...)  xg chunk [t][bl][40], stored[4u+ty] = gate col ty*10+u
#define Bsz 4096
#define Tlen 200
#define INs 79
#define Hs 10
#define Gs 40

__global__ void prep_kernel(const float* __restrict__ wih_mu, const float* __restrict__ wih_rho, const float* __restrict__ wih_eps,
                            const float* __restrict__ whh_mu, const float* __restrict__ whh_rho, const float* __restrict__ whh_eps,
                            const float* __restrict__ b_mu,   const float* __restrict__ b_rho,   const float* __restrict__ b_eps,
                            float* __restrict__ w) {
    int i = blockIdx.x * 256 + threadIdx.x;
    if (i >= 3600) return;
    const float *mu, *rho, *eps; int k;
    if (i < 3160)      { mu = wih_mu; rho = wih_rho; eps = wih_eps; k = i; }
    else if (i < 3560) { mu = whh_mu; rho = whh_rho; eps = whh_eps; k = i - 3160; }
    else               { mu = b_mu;   rho = b_rho;   eps = b_eps;   k = i - 3560; }
    float r = rho[k];
    float sp = (r > 20.0f) ? r : log1pf(expf(r));   // softplus, stable
    float val = fmaf(sp, eps[k], mu[k]);
    int dst;
    if (i < 3160) {                 // Wih element (row r=i/40, col c=i%40)
        int rr = i / 40, c = i % 40;
        int ty = c / 10, u = c % 10;
        dst = ty * 790 + rr * 10 + u;
    } else dst = i;                 // Whh, bias natural
    w[dst] = val;
}

// Projection: 4 waves/block share one staged 64-row tile; wave ty computes
// gate columns [ty*10, ty*10+10). LDS 20224B/block -> 8 blocks/CU = 8 waves/SIMD.
// Weights stream as s_load (uniform base via readfirstlane, contiguous layout).
__global__ __launch_bounds__(256, 8) void proj_kernel(
    const float* __restrict__ x, const float* __restrict__ w,
    float* __restrict__ xg, int b0, int bc) {
    __shared__ __align__(16) float lx[64 * INs];        // 20224 B, contiguous tile
    const int tid = threadIdx.x;
    const int lane = tid & 63;
    const int ty = __builtin_amdgcn_readfirstlane(tid >> 6);  // force SGPR-uniform

    const long row0 = (long)blockIdx.x * 64;            // 64 consecutive (b,t) rows
    const float* src = x + ((long)b0 * Tlen + row0) * INs;   // 16B-aligned (b0%8==0, row0%64==0)
    auto* gsrc = (const __attribute__((address_space(1))) char*)src;
    auto* ldst = (__attribute__((address_space(3))) char*)lx;
    // 64*79 floats = 1264 float4: 4 full rounds of 256 + 240 tail, width-16 gload_lds
#pragma unroll
    for (int k = 0; k < 4; ++k)
        __builtin_amdgcn_global_load_lds(
            (const __attribute__((address_space(1))) void*)(gsrc + (k * 256 + tid) * 16),
            (__attribute__((address_space(3))) void*)(ldst + (k * 256 + tid) * 16), 16, 0, 0);
    if (tid < 240)
        __builtin_amdgcn_global_load_lds(
            (const __attribute__((address_space(1))) void*)(gsrc + (1024 + tid) * 16),
            (__attribute__((address_space(3))) void*)(ldst + (1024 + tid) * 16), 16, 0, 0);
    __syncthreads();

    const float* wp = w + ty * 790;                     // this wave's 79x10 panel (s_load)
    const float* bp = w + 3560 + ty * 10;
    float acc[10];
#pragma unroll
    for (int u = 0; u < 10; ++u) acc[u] = bp[u];
    const float* xr = lx + lane * INs;                  // stride-79 LDS rows: conflict-free
#pragma unroll
    for (int i = 0; i < INs; ++i) {
        float xv = xr[i];
#pragma unroll
        for (int u = 0; u < 10; ++u) acc[u] = fmaf(xv, wp[i * 10 + u], acc[u]);
    }
    long rg = row0 + lane;
    int bl = (int)(rg / Tlen), t = (int)(rg % Tlen);
    float* dst = xg + ((long)t * bc + bl) * Gs + ty;    // stored[4u+ty] = col ty*10+u
#pragma unroll
    for (int u = 0; u < 10; ++u) dst[4 * u] = acc[u];
}

// Recurrence: one wave per batch row. Lane j<40: unit u=j>>2, type ty=j&3
// (ty: 0=i, 1=f, 2=g, 3=o). h broadcast via readlane; gate combine via DPP
// quad_perm. Distance-4 prefetch ring (named regs) covers L3 latency.
__global__ __launch_bounds__(256, 4) void rec_kernel(
    const float* __restrict__ xg, const float* __restrict__ w,
    const float* __restrict__ lin_w, const float* __restrict__ lin_b,
    float* __restrict__ out, int b0, int bc) {
    const int lane = threadIdx.x & 63;
    const int bl = blockIdx.x * 4 + (threadIdx.x >> 6);
    if (bl >= bc) return;
    const int j = lane;
    int pj = (j & 3) * 10 + (j >> 2); pj = pj > 39 ? 39 : pj;  // clamp lanes 40..63
    float wc[Hs];
#pragma unroll
    for (int k = 0; k < Hs; ++k) wc[k] = w[3160 + k * Gs + pj];
    const int ty = j & 3;
    const float sA = (ty == 2) ? -2.0f : -1.0f;
    const float sM = (ty == 2) ?  2.0f :  1.0f;
    const float sC = (ty == 2) ? -1.0f :  0.0f;
    float hs[Hs];
#pragma unroll
    for (int k = 0; k < Hs; ++k) hs[k] = 0.0f;
    float c = 0.0f;

    const long sT = (long)bc * Gs;
    const float* base = xg + (long)bl * Gs + j;

#define STEP(GV)                                                                         \
    {                                                                                    \
        float acc = (GV);                                                                \
        _Pragma("unroll")                                                                \
        for (int k = 0; k < Hs; ++k) acc = fmaf(hs[k], wc[k], acc);                      \
        float e  = __expf(acc * sA);                                                     \
        float sg = __builtin_amdgcn_rcpf(1.0f + e);                                      \
        float act = fmaf(sg, sM, sC);                                                    \
        int ai = __float_as_int(act);                                                    \
        float a1d = __int_as_float(__builtin_amdgcn_mov_dpp(ai, 0xB1, 0xF, 0xF, true));  \
        float a2d = __int_as_float(__builtin_amdgcn_mov_dpp(ai, 0x4E, 0xF, 0xF, true));  \
        float a3d = __int_as_float(__builtin_amdgcn_mov_dpp(ai, 0x1B, 0xF, 0xF, true));  \
        c = fmaf(a1d, c, act * a2d);                                                     \
        float e2 = __expf(-2.0f * c);                                                    \
        float th = fmaf(2.0f, __builtin_amdgcn_rcpf(1.0f + e2), -1.0f);                  \
        float hn = a3d * th;                                                             \
        _Pragma("unroll")                                                                \
        for (int k = 0; k < Hs; ++k)                                                     \
            hs[k] = __int_as_float(__builtin_amdgcn_readlane(__float_as_int(hn), 4 * k));\
    }

    float g0 = base[0];
    float g1 = base[sT];
    float g2 = base[2 * sT];
    float g3 = base[3 * sT];
    for (int t = 0; t < Tlen; t += 4) {
        int t4 = t + 4 < Tlen ? t + 4 : Tlen - 1;
        int t5 = t + 5 < Tlen ? t + 5 : Tlen - 1;
        int t6 = t + 6 < Tlen ? t + 6 : Tlen - 1;
        int t7 = t + 7 < Tlen ? t + 7 : Tlen - 1;
        float n0 = base[(long)t4 * sT];
        float n1 = base[(long)t5 * sT];
        float n2 = base[(long)t6 * sT];
        float n3 = base[(long)t7 * sT];
        STEP(g0); STEP(g1); STEP(g2); STEP(g3);
        g0 = n0; g1 = n1; g2 = n2; g3 = n3;
    }
#undef STEP
    if (lane == 0) {
        float o = lin_b[0];
#pragma unroll
        for (int k = 0; k < Hs; ++k) o = fmaf(hs[k], lin_w[k], o);
        out[b0 + bl] = o;
    }
}

extern "C" void kernel_launch(void* const* d_in, const int* in_sizes, int n_in,
                              void* d_out, int out_size, void* d_ws, size_t ws_size,
                              hipStream_t stream) {
    const float* x = (const float*)d_in[0];
    float* w   = (float*)d_ws;
    float* out = (float*)d_out;

    prep_kernel<<<15, 256, 0, stream>>>(
        (const float*)d_in[1], (const float*)d_in[2], (const float*)d_in[3],
        (const float*)d_in[4], (const float*)d_in[5], (const float*)d_in[6],
        (const float*)d_in[7], (const float*)d_in[8], (const float*)d_in[9], w);

    // b-chunk so xg (bc*T*G floats) fits in ws; bc multiple of 8 so bc*T % 64 == 0.
    long avail = (long)(ws_size / 4);
    long per_b = (long)Tlen * Gs;                 // 8000 floats per batch row
    long bcL = (avail - 4096 - 64) / per_b;
    int bc = (bcL >= Bsz) ? Bsz : (int)(bcL - (bcL % 8));
    if (bc < 8) bc = 8;
    float* xg = w + 4096;

    for (int b0 = 0; b0 < Bsz; b0 += bc) {
        int cur = (Bsz - b0 < bc) ? (Bsz - b0) : bc;
        int pblocks = (int)((long)cur * Tlen / 64);   // one 64-row tile per block
        proj_kernel<<<pblocks, 256, 0, stream>>>(x, w, xg, b0, cur);
        rec_kernel<<<cur / 4, 256, 0, stream>>>(
            xg, w, (const float*)d_in[10], (const float*)d_in[11], out, b0, cur);
    }
}

// Round 5
// 176.803 us; speedup vs baseline: 2.7450x; 1.4264x over previous
//
#include <hip/hip_runtime.h>
#include <cstdint>

// Bayesian LSTM: B=4096, T=200, IN=79, H=10 (gates G=40)
// proj = GEMM [B*T,79]x[79,40] via bf16 hi/lo split MFMA (3-term, ~3e-6 err).
// ws float layout:
//  [0,48)      bias_hat f32, gates 0..39, zero-padded to 48
//  [48,448)    Whh_hat f32 natural: 48 + k*40 + c
//  [512,2816)  Bh: bf16(W) as ushort[48][96], c-major (c*96+k), zero-padded
//  [2816,5120) Bl: bf16(W - float(Bh)) same layout
//  [8192,...)  xg chunk, linear [local_rg][40]  (local_rg = bl*200 + t)
#define Bsz 4096
#define Tlen 200
#define INs 79
#define Hs 10
#define Gs 40

typedef __attribute__((ext_vector_type(8))) short bf16x8;
typedef __attribute__((ext_vector_type(4))) float f32x4;

__device__ __forceinline__ unsigned short f2bf(float x) {   // RNE f32->bf16
    unsigned u = __float_as_uint(x);
    return (unsigned short)((u + 0x7FFF + ((u >> 16) & 1)) >> 16);
}

__global__ void prep_kernel(const float* __restrict__ wih_mu, const float* __restrict__ wih_rho, const float* __restrict__ wih_eps,
                            const float* __restrict__ whh_mu, const float* __restrict__ whh_rho, const float* __restrict__ whh_eps,
                            const float* __restrict__ b_mu,   const float* __restrict__ b_rho,   const float* __restrict__ b_eps,
                            float* __restrict__ w) {
    int idx = blockIdx.x * 256 + threadIdx.x;
    if (idx < 4608) {                       // Wih -> Bh/Bl bf16 split, [48][96] c-major
        int c = idx / 96, k = idx % 96;
        float val = 0.0f;
        if (c < Gs && k < INs) {
            int s = k * Gs + c;
            float r = wih_rho[s];
            float sp = (r > 20.0f) ? r : log1pf(expf(r));
            val = fmaf(sp, wih_eps[s], wih_mu[s]);
        }
        unsigned short h = f2bf(val);
        float back = __uint_as_float((unsigned)h << 16);
        unsigned short l = f2bf(val - back);
        ((unsigned short*)(w + 512))[idx]  = h;
        ((unsigned short*)(w + 2816))[idx] = l;
    } else if (idx < 5008) {                // Whh f32 natural
        int m = idx - 4608;
        float r = whh_rho[m];
        float sp = (r > 20.0f) ? r : log1pf(expf(r));
        w[48 + m] = fmaf(sp, whh_eps[m], whh_mu[m]);
    } else if (idx < 5056) {                // bias f32, padded to 48
        int m = idx - 5008;
        float val = 0.0f;
        if (m < Gs) {
            float r = b_rho[m];
            float sp = (r > 20.0f) ? r : log1pf(expf(r));
            val = fmaf(sp, b_eps[m], b_mu[m]);
        }
        w[m] = val;
    }
}

// proj: 64 rows/block, 4 waves; wave wv owns rows [wv*16, wv*16+16).
// A-frag: lane L -> X[row=L&15][k0+(L>>4)*8+e]; B-frag: lane L -> W[k][col=L&15];
// D: lane L reg r -> [row=(L>>4)*4+r][col=L&15]. 3 k-steps (K=96), 3 N-tiles (48).
__global__ __launch_bounds__(256, 6) void proj_kernel(
    const float* __restrict__ x, const float* __restrict__ w,
    float* __restrict__ xg, int b0, int bc) {
    __shared__ __align__(16) float lx[64 * INs + 32];   // +pad: ks=2 reads overrun, masked
    const int tid = threadIdx.x;
    const int lane = tid & 63;
    const int wv = __builtin_amdgcn_readfirstlane(tid >> 6);

    const long row0 = (long)blockIdx.x * 64;
    const float* src = x + ((long)b0 * Tlen + row0) * INs;
    auto* gsrc = (const __attribute__((address_space(1))) char*)src;
    auto* ldst = (__attribute__((address_space(3))) char*)lx;
#pragma unroll
    for (int k = 0; k < 4; ++k)
        __builtin_amdgcn_global_load_lds(
            (const __attribute__((address_space(1))) void*)(gsrc + (k * 256 + tid) * 16),
            (__attribute__((address_space(3))) void*)(ldst + (k * 256 + tid) * 16), 16, 0, 0);
    if (tid < 240)
        __builtin_amdgcn_global_load_lds(
            (const __attribute__((address_space(1))) void*)(gsrc + (1024 + tid) * 16),
            (__attribute__((address_space(3))) void*)(ldst + (1024 + tid) * 16), 16, 0, 0);
    __syncthreads();

    const int jj = lane & 15;
    const int kg8 = (lane >> 4) * 8;
    const unsigned short* Bh = (const unsigned short*)(w + 512);
    const unsigned short* Bl = (const unsigned short*)(w + 2816);

    f32x4 acc[3];
#pragma unroll
    for (int n = 0; n < 3; ++n) {
        float bv = w[n * 16 + jj];          // bias (padded region zero)
        acc[n] = (f32x4){bv, bv, bv, bv};
    }

    const float* xr = lx + (wv * 16 + jj) * INs;
#pragma unroll
    for (int ks = 0; ks < 3; ++ks) {
        const int k0 = ks * 32;
        float f[8];
#pragma unroll
        for (int e = 0; e < 8; ++e) {
            float v = xr[k0 + kg8 + e];
            if (ks == 2) v = (k0 + kg8 + e < INs) ? v : 0.0f;  // mask pad K (B is 0 there too)
            f[e] = v;
        }
        union { unsigned u[4]; bf16x8 v; } Ah, Al;
#pragma unroll
        for (int p = 0; p < 4; ++p) {
            float a = f[2 * p], b = f[2 * p + 1];
            unsigned short ha = f2bf(a), hb = f2bf(b);
            float ra = __uint_as_float((unsigned)ha << 16);
            float rb = __uint_as_float((unsigned)hb << 16);
            unsigned short la = f2bf(a - ra), lb = f2bf(b - rb);
            Ah.u[p] = (unsigned)ha | ((unsigned)hb << 16);
            Al.u[p] = (unsigned)la | ((unsigned)lb << 16);
        }
#pragma unroll
        for (int n = 0; n < 3; ++n) {
            int boff = (n * 16 + jj) * 96 + k0 + kg8;      // 16B-aligned
            bf16x8 bh = *(const bf16x8*)(Bh + boff);
            bf16x8 bl = *(const bf16x8*)(Bl + boff);
            acc[n] = __builtin_amdgcn_mfma_f32_16x16x32_bf16(Ah.v, bh, acc[n], 0, 0, 0);
            acc[n] = __builtin_amdgcn_mfma_f32_16x16x32_bf16(Ah.v, bl, acc[n], 0, 0, 0);
            acc[n] = __builtin_amdgcn_mfma_f32_16x16x32_bf16(Al.v, bh, acc[n], 0, 0, 0);
        }
    }
    // D store: rows (lane>>4)*4+r, col n*16+jj; xg linear [rg][40]
    const long gr = row0 + wv * 16 + (lane >> 4) * 4;
    float* orow = xg + gr * Gs + jj;
#pragma unroll
    for (int n = 0; n < 3; ++n) {
        if (n == 2 && jj >= 8) continue;    // gates 40..47 are padding
#pragma unroll
        for (int r = 0; r < 4; ++r)
            orow[(long)r * Gs + n * 16] = acc[n][r];
    }
}

// rec: one wave per batch row; lane j<40: u=j>>2, ty=j&3 (0=i,1=f,2=g,3=o);
// reads xg slot pj = ty*10+u (plain gate order). DPP quad_perm combine,
// readlane h-broadcast, distance-4 prefetch ring.
__global__ __launch_bounds__(256, 4) void rec_kernel(
    const float* __restrict__ xg, const float* __restrict__ w,
    const float* __restrict__ lin_w, const float* __restrict__ lin_b,
    float* __restrict__ out, int b0, int bc) {
    const int lane = threadIdx.x & 63;
    const int bl = blockIdx.x * 4 + (threadIdx.x >> 6);
    if (bl >= bc) return;
    const int j = lane;
    int pj = (j & 3) * 10 + (j >> 2); pj = pj > 39 ? 39 : pj;
    float wc[Hs];
#pragma unroll
    for (int k = 0; k < Hs; ++k) wc[k] = w[48 + k * Gs + pj];
    const int ty = j & 3;
    const float sA = (ty == 2) ? -2.0f : -1.0f;
    const float sM = (ty == 2) ?  2.0f :  1.0f;
    const float sC = (ty == 2) ? -1.0f :  0.0f;
    float hs[Hs];
#pragma unroll
    for (int k = 0; k < Hs; ++k) hs[k] = 0.0f;
    float c = 0.0f;

    const float* base = xg + (long)bl * (Tlen * Gs) + pj;

#define STEP(GV)                                                                         \
    {                                                                                    \
        float acc = (GV);                                                                \
        _Pragma("unroll")                                                                \
        for (int k = 0; k < Hs; ++k) acc = fmaf(hs[k], wc[k], acc);                      \
        float e  = __expf(acc * sA);                                                     \
        float sg = __builtin_amdgcn_rcpf(1.0f + e);                                      \
        float act = fmaf(sg, sM, sC);                                                    \
        int ai = __float_as_int(act);                                                    \
        float a1d = __int_as_float(__builtin_amdgcn_mov_dpp(ai, 0xB1, 0xF, 0xF, true));  \
        float a2d = __int_as_float(__builtin_amdgcn_mov_dpp(ai, 0x4E, 0xF, 0xF, true));  \
        float a3d = __int_as_float(__builtin_amdgcn_mov_dpp(ai, 0x1B, 0xF, 0xF, true));  \
        c = fmaf(a1d, c, act * a2d);                                                     \
        float e2 = __expf(-2.0f * c);                                                    \
        float th = fmaf(2.0f, __builtin_amdgcn_rcpf(1.0f + e2), -1.0f);                  \
        float hn = a3d * th;                                                             \
        _Pragma("unroll")                                                                \
        for (int k = 0; k < Hs; ++k)                                                     \
            hs[k] = __int_as_float(__builtin_amdgcn_readlane(__float_as_int(hn), 4 * k));\
    }

    float g0 = base[0];
    float g1 = base[Gs];
    float g2 = base[2 * Gs];
    float g3 = base[3 * Gs];
    for (int t = 0; t < Tlen; t += 4) {
        int t4 = t + 4 < Tlen ? t + 4 : Tlen - 1;
        int t5 = t + 5 < Tlen ? t + 5 : Tlen - 1;
        int t6 = t + 6 < Tlen ? t + 6 : Tlen - 1;
        int t7 = t + 7 < Tlen ? t + 7 : Tlen - 1;
        float n0 = base[t4 * Gs];
        float n1 = base[t5 * Gs];
        float n2 = base[t6 * Gs];
        float n3 = base[t7 * Gs];
        STEP(g0); STEP(g1); STEP(g2); STEP(g3);
        g0 = n0; g1 = n1; g2 = n2; g3 = n3;
    }
#undef STEP
    if (lane == 0) {
        float o = lin_b[0];
#pragma unroll
        for (int k = 0; k < Hs; ++k) o = fmaf(hs[k], lin_w[k], o);
        out[b0 + bl] = o;
    }
}

extern "C" void kernel_launch(void* const* d_in, const int* in_sizes, int n_in,
                              void* d_out, int out_size, void* d_ws, size_t ws_size,
                              hipStream_t stream) {
    const float* x = (const float*)d_in[0];
    float* w   = (float*)d_ws;
    float* out = (float*)d_out;

    prep_kernel<<<20, 256, 0, stream>>>(
        (const float*)d_in[1], (const float*)d_in[2], (const float*)d_in[3],
        (const float*)d_in[4], (const float*)d_in[5], (const float*)d_in[6],
        (const float*)d_in[7], (const float*)d_in[8], (const float*)d_in[9], w);

    // b-chunk so xg (bc*T*G floats) fits in ws; bc multiple of 8 so bc*T % 64 == 0.
    long avail = (long)(ws_size / 4);
    long per_b = (long)Tlen * Gs;                 // 8000 floats per batch row
    long bcL = (avail - 8192 - 64) / per_b;
    int bc = (bcL >= Bsz) ? Bsz : (int)(bcL - (bcL % 8));
    if (bc < 8) bc = 8;
    float* xg = w + 8192;

    for (int b0 = 0; b0 < Bsz; b0 += bc) {
        int cur = (Bsz - b0 < bc) ? (Bsz - b0) : bc;
        int pblocks = (int)((long)cur * Tlen / 64);   // one 64-row tile per block
        proj_kernel<<<pblocks, 256, 0, stream>>>(x, w, xg, b0, cur);
        rec_kernel<<<cur / 4, 256, 0, stream>>>(
            xg, w, (const float*)d_in[10], (const float*)d_in[11], out, b0, cur);
    }
}

// Round 7
// 107.160 us; speedup vs baseline: 4.5289x; 1.6499x over previous
//
#include <hip/hip_runtime.h>
#include <cstdint>

// Fused Bayesian LSTM: B=4096, T=200, IN=79, H=10 (gates G=40)
// proj = per-wave MFMA GEMM tile [16x79]x[79x40] (bf16 hi/lo 3-term split),
// fused with the recurrence: one wave per batch row, no xg round-trip.
// ws float layout (from prep):
//  [0,48)      bias_hat f32, gates 0..39, zero-padded to 48
//  [48,448)    Whh_hat f32 natural: 48 + k*40 + c
//  [512,2816)  Bh: bf16(W) as ushort[48][96], c-major (c*96+k), zero-padded
//  [2816,5120) Bl: bf16(W - float(Bh)) same layout
#define Bsz 4096
#define Tlen 200
#define INs 79
#define Hs 10
#define Gs 40

typedef __attribute__((ext_vector_type(8))) short bf16x8;
typedef __attribute__((ext_vector_type(4))) float f32x4;

__device__ __forceinline__ unsigned short f2bf(float x) {   // RNE f32->bf16
    unsigned u = __float_as_uint(x);
    return (unsigned short)((u + 0x7FFF + ((u >> 16) & 1)) >> 16);
}

__global__ void prep_kernel(const float* __restrict__ wih_mu, const float* __restrict__ wih_rho, const float* __restrict__ wih_eps,
                            const float* __restrict__ whh_mu, const float* __restrict__ whh_rho, const float* __restrict__ whh_eps,
                            const float* __restrict__ b_mu,   const float* __restrict__ b_rho,   const float* __restrict__ b_eps,
                            float* __restrict__ w) {
    int idx = blockIdx.x * 256 + threadIdx.x;
    if (idx < 4608) {                       // Wih -> Bh/Bl bf16 split, [48][96] c-major
        int c = idx / 96, k = idx % 96;
        float val = 0.0f;
        if (c < Gs && k < INs) {
            int s = k * Gs + c;
            float r = wih_rho[s];
            float sp = (r > 20.0f) ? r : log1pf(expf(r));
            val = fmaf(sp, wih_eps[s], wih_mu[s]);
        }
        unsigned short h = f2bf(val);
        float back = __uint_as_float((unsigned)h << 16);
        unsigned short l = f2bf(val - back);
        ((unsigned short*)(w + 512))[idx]  = h;
        ((unsigned short*)(w + 2816))[idx] = l;
    } else if (idx < 5008) {                // Whh f32 natural
        int m = idx - 4608;
        float r = whh_rho[m];
        float sp = (r > 20.0f) ? r : log1pf(expf(r));
        w[48 + m] = fmaf(sp, whh_eps[m], whh_mu[m]);
    } else if (idx < 5056) {                // bias f32, padded to 48
        int m = idx - 5008;
        float val = 0.0f;
        if (m < Gs) {
            float r = b_rho[m];
            float sp = (r > 20.0f) ? r : log1pf(expf(r));
            val = fmaf(sp, b_eps[m], b_mu[m]);
        }
        w[m] = val;
    }
}

// One wave (64-thread block) per batch row b = blockIdx.x.
// Per 16-timestep tile: [vmcnt(0)] -> 24 A ds_reads -> lgkmcnt(0) ->
// async-stage next tile -> bf16 conv -> 27 MFMA -> gates to LDS (stride 42)
// -> 16 recurrence steps (DPP quad combine + readlane h-broadcast).
__global__ __launch_bounds__(64, 4) void fused_kernel(
    const float* __restrict__ x, const float* __restrict__ w,
    const float* __restrict__ lin_w, const float* __restrict__ lin_b,
    float* __restrict__ out) {
    __shared__ __align__(16) float sm[1264 + 16 * 42];  // xbuf[16*79] | gbuf[16][42]
    float* xbuf = sm;
    float* gbuf = sm + 1264;

    const int b = blockIdx.x;
    const int lane = threadIdx.x;
    const int jj = lane & 15;
    const int kg8 = (lane >> 4) * 8;

    const unsigned short* Bh = (const unsigned short*)(w + 512);
    const unsigned short* Bl = (const unsigned short*)(w + 2816);

    int pj = (lane & 3) * 10 + (lane >> 2); if (pj > 39) pj = 39;  // gate col; clamp lanes >39
    float wc[Hs];
#pragma unroll
    for (int k = 0; k < Hs; ++k) wc[k] = w[48 + k * Gs + pj];      // Whh column
    const int ty = lane & 3;
    const float sA = (ty == 2) ? -2.0f : -1.0f;
    const float sM = (ty == 2) ?  2.0f :  1.0f;
    const float sC = (ty == 2) ? -1.0f :  0.0f;

    float hs[Hs];
#pragma unroll
    for (int k = 0; k < Hs; ++k) hs[k] = 0.0f;
    float cc = 0.0f;

    const long xbaseB = (long)b * (Tlen * INs) * 4;                 // bytes, 16B-aligned
    const long xendB  = (long)Bsz * Tlen * INs * 4 - 16;            // last valid 16B slot
    auto* ldsc = (__attribute__((address_space(3))) char*)xbuf;

    auto stage = [&](int t0) {   // 16 rows x 79 f32 = 316 x 16B slots, linear LDS dest
        long srcB = xbaseB + (long)t0 * INs * 4;                    // 16B-aligned (t0%16==0)
#pragma unroll
        for (int kk = 0; kk < 4; ++kk) {
            long off = srcB + (long)(kk * 64 + lane) * 16;
            if (off > xendB) off = xendB;                           // clamp at array end
            __builtin_amdgcn_global_load_lds(
                (const __attribute__((address_space(1))) void*)((const char*)x + off),
                (__attribute__((address_space(3))) void*)(ldsc + (kk * 64 + lane) * 16), 16, 0, 0);
        }
        if (lane < 60) {
            long off = srcB + (long)(256 + lane) * 16;
            if (off > xendB) off = xendB;
            __builtin_amdgcn_global_load_lds(
                (const __attribute__((address_space(1))) void*)((const char*)x + off),
                (__attribute__((address_space(3))) void*)(ldsc + (256 + lane) * 16), 16, 0, 0);
        }
    };

    stage(0);

    for (int tile = 0; tile < 13; ++tile) {
        const int t0 = tile * 16;
        asm volatile("s_waitcnt vmcnt(0)" ::: "memory");   // staged tile ready

        // ---- A-fragment reads (f32) from LDS; mask K-pad (k>=79) to 0 ----
        float f0[8], f1[8], f2[8];
#pragma unroll
        for (int e = 0; e < 8; ++e) f0[e] = xbuf[jj * INs + kg8 + e];
#pragma unroll
        for (int e = 0; e < 8; ++e) f1[e] = xbuf[jj * INs + 32 + kg8 + e];
#pragma unroll
        for (int e = 0; e < 8; ++e) {
            float raw = xbuf[jj * INs + 64 + kg8 + e];     // may read past row: masked below
            f2[e] = (kg8 + e < 15) ? raw : 0.0f;           // k=64+kg8+e < 79 (NaN-safe)
        }
        asm volatile("s_waitcnt lgkmcnt(0)" ::: "memory"); // A data in regs -> xbuf reusable
        if (tile < 12) stage(t0 + 16);                     // async prefetch next tile

        // ---- f32 -> bf16 hi/lo fragments ----
        union { unsigned u[4]; bf16x8 v; } Ah[3], Al[3];
        const float* fp[3] = {f0, f1, f2};
#pragma unroll
        for (int ks = 0; ks < 3; ++ks) {
#pragma unroll
            for (int p = 0; p < 4; ++p) {
                float a = fp[ks][2 * p], bb = fp[ks][2 * p + 1];
                unsigned short ha = f2bf(a), hbv = f2bf(bb);
                float ra = __uint_as_float((unsigned)ha << 16);
                float rb = __uint_as_float((unsigned)hbv << 16);
                unsigned short la = f2bf(a - ra), lb = f2bf(bb - rb);
                Ah[ks].u[p] = (unsigned)ha | ((unsigned)hbv << 16);
                Al[ks].u[p] = (unsigned)la | ((unsigned)lb << 16);
            }
        }

        // ---- 27 MFMA: 3 K-steps x 3 N-tiles x 3 terms ----
        f32x4 acc[3];
#pragma unroll
        for (int n = 0; n < 3; ++n) {
            float bv = w[n * 16 + jj];                     // bias (pad region zero)
            acc[n] = (f32x4){bv, bv, bv, bv};
        }
#pragma unroll
        for (int ks = 0; ks < 3; ++ks) {
            const int k0 = ks * 32;
#pragma unroll
            for (int n = 0; n < 3; ++n) {
                int boff = (n * 16 + jj) * 96 + k0 + kg8;  // 16B-aligned
                bf16x8 bh = *(const bf16x8*)(Bh + boff);
                bf16x8 bl = *(const bf16x8*)(Bl + boff);
                acc[n] = __builtin_amdgcn_mfma_f32_16x16x32_bf16(Ah[ks].v, bh, acc[n], 0, 0, 0);
                acc[n] = __builtin_amdgcn_mfma_f32_16x16x32_bf16(Ah[ks].v, bl, acc[n], 0, 0, 0);
                acc[n] = __builtin_amdgcn_mfma_f32_16x16x32_bf16(Al[ks].v, bh, acc[n], 0, 0, 0);
            }
        }

        // ---- gates -> LDS tile [16][42] (D row=(lane>>4)*4+r = timestep, col=n*16+jj) ----
#pragma unroll
        for (int n = 0; n < 3; ++n) {
            if (n == 2 && jj >= 8) continue;               // cols 40..47 are padding
#pragma unroll
            for (int r = 0; r < 4; ++r)
                gbuf[((lane >> 4) * 4 + r) * 42 + n * 16 + jj] = acc[n][r];
        }
        // ---- pre-read this tile's 16 gates for lane's gate column pj ----
        float gv[16];
#pragma unroll
        for (int tt = 0; tt < 16; ++tt) gv[tt] = gbuf[tt * 42 + pj];

        // ---- recurrence ----
#pragma unroll
        for (int tt = 0; tt < 16; ++tt) {
            if (t0 + tt < Tlen) {
                float acs = gv[tt];
#pragma unroll
                for (int k = 0; k < Hs; ++k) acs = fmaf(hs[k], wc[k], acs);
                float e  = __expf(acs * sA);
                float sg = __builtin_amdgcn_rcpf(1.0f + e);
                float act = fmaf(sg, sM, sC);              // sigmoid(i,f,o) / tanh(g)
                int ai = __float_as_int(act);
                float a1d = __int_as_float(__builtin_amdgcn_mov_dpp(ai, 0xB1, 0xF, 0xF, true));
                float a2d = __int_as_float(__builtin_amdgcn_mov_dpp(ai, 0x4E, 0xF, 0xF, true));
                float a3d = __int_as_float(__builtin_amdgcn_mov_dpp(ai, 0x1B, 0xF, 0xF, true));
                cc = fmaf(a1d, cc, act * a2d);             // c = f*c + i*g (valid ty==0)
                float e2 = __expf(-2.0f * cc);
                float th = fmaf(2.0f, __builtin_amdgcn_rcpf(1.0f + e2), -1.0f);
                float hn = a3d * th;                       // h = o * tanh(c)
#pragma unroll
                for (int k = 0; k < Hs; ++k)
                    hs[k] = __int_as_float(__builtin_amdgcn_readlane(__float_as_int(hn), 4 * k));
            }
        }
    }

    if (lane == 0) {
        float o = lin_b[0];
#pragma unroll
        for (int k = 0; k < Hs; ++k) o = fmaf(hs[k], lin_w[k], o);
        out[b] = o;
    }
}

extern "C" void kernel_launch(void* const* d_in, const int* in_sizes, int n_in,
                              void* d_out, int out_size, void* d_ws, size_t ws_size,
                              hipStream_t stream) {
    const float* x = (const float*)d_in[0];
    float* w   = (float*)d_ws;
    float* out = (float*)d_out;

    prep_kernel<<<20, 256, 0, stream>>>(
        (const float*)d_in[1], (const float*)d_in[2], (const float*)d_in[3],
        (const float*)d_in[4], (const float*)d_in[5], (const float*)d_in[6],
        (const float*)d_in[7], (const float*)d_in[8], (const float*)d_in[9], w);

    fused_kernel<<<Bsz, 64, 0, stream>>>(
        x, w, (const float*)d_in[10], (const float*)d_in[11], out);
}

// Round 9
// 105.847 us; speedup vs baseline: 4.5851x; 1.0124x over previous
//
#include <hip/hip_runtime.h>
#include <cstdint>

// Fused Bayesian LSTM: B=4096, T=200, IN=79, H=10 (gates G=40)
// proj = per-wave MFMA GEMM tile [16x79]x[79x40] (bf16 trunc-hi/RNE-lo split),
// fused with the recurrence: one wave per batch row, no xg round-trip.
// ws float layout (from prep):
//  [0,48)      bias_hat f32, gates 0..39, zero-padded to 48
//  [48,448)    Whh_hat f32 natural: 48 + k*40 + c
//  [512,2816)  Bh: bf16(W) as ushort[48][96], c-major (c*96+k), zero-padded
//  [2816,5120) Bl: bf16(W - float(Bh)) same layout
#define Bsz 4096
#define Tlen 200
#define INs 79
#define Hs 10
#define Gs 40

typedef __attribute__((ext_vector_type(8))) short bf16x8;
typedef __attribute__((ext_vector_type(4))) float f32x4;

__device__ __forceinline__ unsigned short f2bf(float x) {   // RNE f32->bf16
    unsigned u = __float_as_uint(x);
    return (unsigned short)((u + 0x7FFF + ((u >> 16) & 1)) >> 16);
}

__global__ void prep_kernel(const float* __restrict__ wih_mu, const float* __restrict__ wih_rho, const float* __restrict__ wih_eps,
                            const float* __restrict__ whh_mu, const float* __restrict__ whh_rho, const float* __restrict__ whh_eps,
                            const float* __restrict__ b_mu,   const float* __restrict__ b_rho,   const float* __restrict__ b_eps,
                            float* __restrict__ w) {
    int idx = blockIdx.x * 256 + threadIdx.x;
    if (idx < 4608) {                       // Wih -> Bh/Bl bf16 split, [48][96] c-major
        int c = idx / 96, k = idx % 96;
        float val = 0.0f;
        if (c < Gs && k < INs) {
            int s = k * Gs + c;
            float r = wih_rho[s];
            float sp = (r > 20.0f) ? r : log1pf(expf(r));
            val = fmaf(sp, wih_eps[s], wih_mu[s]);
        }
        unsigned short h = f2bf(val);
        float back = __uint_as_float((unsigned)h << 16);
        unsigned short l = f2bf(val - back);
        ((unsigned short*)(w + 512))[idx]  = h;
        ((unsigned short*)(w + 2816))[idx] = l;
    } else if (idx < 5008) {                // Whh f32 natural
        int m = idx - 4608;
        float r = whh_rho[m];
        float sp = (r > 20.0f) ? r : log1pf(expf(r));
        w[48 + m] = fmaf(sp, whh_eps[m], whh_mu[m]);
    } else if (idx < 5056) {                // bias f32, padded to 48
        int m = idx - 5008;
        float val = 0.0f;
        if (m < Gs) {
            float r = b_rho[m];
            float sp = (r > 20.0f) ? r : log1pf(expf(r));
            val = fmaf(sp, b_eps[m], b_mu[m]);
        }
        w[m] = val;
    }
}

// One wave (64-thread block) per batch row b = blockIdx.x.
// Per 16-timestep tile: vmcnt(0) -> A ds_reads -> lgkmcnt(0) -> async-stage
// next tile -> cheap bf16 split (perm/and/sub/cvt_pk, 6 ops per 2 elems) ->
// 27 MFMA -> gates via LDS bounce -> 16 recurrence steps (DPP quad combine +
// readlane h-broadcast, sA pre-folded into weights/gates).
__global__ __launch_bounds__(64, 4) void fused_kernel(
    const float* __restrict__ x, const float* __restrict__ w,
    const float* __restrict__ lin_w, const float* __restrict__ lin_b,
    float* __restrict__ out) {
    // xbuf[1264] | zpad[16] (zeros: K-pad overread lands here) | gbuf[16][42]
    __shared__ __align__(16) float sm[1280 + 16 * 42];
    float* xbuf = sm;
    float* gbuf = sm + 1280;

    const int b = blockIdx.x;
    const int lane = threadIdx.x;
    const int jj = lane & 15;
    const int kg8 = (lane >> 4) * 8;

    if (lane < 16) sm[1264 + lane] = 0.0f;            // zero the pad once (wave-private)

    const unsigned short* Bh = (const unsigned short*)(w + 512);
    const unsigned short* Bl = (const unsigned short*)(w + 2816);

    int pj = (lane & 3) * 10 + (lane >> 2); if (pj > 39) pj = 39;  // gate col; clamp lanes >39
    const int ty = lane & 3;
    const float sA = (ty == 2) ? -2.0f : -1.0f;       // exact powers of two
    const float sM = (ty == 2) ?  2.0f :  1.0f;
    const float sC = (ty == 2) ? -1.0f :  0.0f;
    float wcs[Hs];
#pragma unroll
    for (int k = 0; k < Hs; ++k) wcs[k] = w[48 + k * Gs + pj] * sA;  // Whh col, sA-folded
    float bias3[3];
#pragma unroll
    for (int n = 0; n < 3; ++n) bias3[n] = w[n * 16 + jj];           // pad region zero

    float hs[Hs];
#pragma unroll
    for (int k = 0; k < Hs; ++k) hs[k] = 0.0f;
    float cc = 0.0f;

    const long xbaseB = (long)b * (Tlen * INs) * 4;                  // bytes, 16B-aligned
    const long xendB  = (long)Bsz * Tlen * INs * 4 - 16;             // last valid 16B slot
    auto* ldsc = (__attribute__((address_space(3))) char*)xbuf;

    auto stage = [&](int t0) {   // 16 rows x 79 f32 = 316 x 16B slots, linear LDS dest
        long srcB = xbaseB + (long)t0 * INs * 4;                     // 16B-aligned
#pragma unroll
        for (int kk = 0; kk < 4; ++kk) {
            long off = srcB + (long)(kk * 64 + lane) * 16;
            if (off > xendB) off = xendB;                            // clamp at array end
            __builtin_amdgcn_global_load_lds(
                (const __attribute__((address_space(1))) void*)((const char*)x + off),
                (__attribute__((address_space(3))) void*)(ldsc + (kk * 64 + lane) * 16), 16, 0, 0);
        }
        if (lane < 60) {
            long off = srcB + (long)(256 + lane) * 16;
            if (off > xendB) off = xendB;
            __builtin_amdgcn_global_load_lds(
                (const __attribute__((address_space(1))) void*)((const char*)x + off),
                (__attribute__((address_space(3))) void*)(ldsc + (256 + lane) * 16), 16, 0, 0);
        }
    };

    stage(0);

    for (int tile = 0; tile < 13; ++tile) {
        const int t0 = tile * 16;
        asm volatile("s_waitcnt vmcnt(0)" ::: "memory");   // staged tile ready

        // ---- A-fragment reads (f32) from LDS; overread past k=79 is finite
        //      (zpad/next-row) and multiplies zero-padded B -> contributes 0 ----
        float f0[8], f1[8], f2[8];
#pragma unroll
        for (int e = 0; e < 8; ++e) f0[e] = xbuf[jj * INs + kg8 + e];
#pragma unroll
        for (int e = 0; e < 8; ++e) f1[e] = xbuf[jj * INs + 32 + kg8 + e];
#pragma unroll
        for (int e = 0; e < 8; ++e) f2[e] = xbuf[jj * INs + 64 + kg8 + e];
        asm volatile("s_waitcnt lgkmcnt(0)" ::: "memory"); // A data in regs -> xbuf reusable
        if (tile < 12) stage(t0 + 16);                     // async prefetch next tile

        // ---- cheap bf16 split: hi = trunc (perm-pack), lo = exact residual
        //      (sub) RNE-packed via v_cvt_pk_bf16_f32. 6 ops per 2 elements. ----
        union { unsigned u[4]; bf16x8 v; } Ah[3], Al[3];
        const float* fp[3] = {f0, f1, f2};
#pragma unroll
        for (int ks = 0; ks < 3; ++ks) {
#pragma unroll
            for (int p = 0; p < 4; ++p) {
                float a = fp[ks][2 * p], bb = fp[ks][2 * p + 1];
                unsigned ua = __float_as_uint(a), ub = __float_as_uint(bb);
                Ah[ks].u[p] = __builtin_amdgcn_perm(ub, ua, 0x07060302);  // {hi(b),hi(a)}
                float ra = a  - __uint_as_float(ua & 0xFFFF0000u);        // exact
                float rb = bb - __uint_as_float(ub & 0xFFFF0000u);        // exact
                unsigned pk;
                asm("v_cvt_pk_bf16_f32 %0, %1, %2" : "=v"(pk) : "v"(ra), "v"(rb));
                Al[ks].u[p] = pk;
            }
        }

        // ---- 27 MFMA: 3 K-steps x 3 N-tiles x 3 terms ----
        f32x4 acc[3];
#pragma unroll
        for (int n = 0; n < 3; ++n)
            acc[n] = (f32x4){bias3[n], bias3[n], bias3[n], bias3[n]};
#pragma unroll
        for (int ks = 0; ks < 3; ++ks) {
            const int k0 = ks * 32;
#pragma unroll
            for (int n = 0; n < 3; ++n) {
                int boff = (n * 16 + jj) * 96 + k0 + kg8;  // 16B-aligned
                bf16x8 bh = *(const bf16x8*)(Bh + boff);
                bf16x8 bl = *(const bf16x8*)(Bl + boff);
                acc[n] = __builtin_amdgcn_mfma_f32_16x16x32_bf16(Ah[ks].v, bh, acc[n], 0, 0, 0);
                acc[n] = __builtin_amdgcn_mfma_f32_16x16x32_bf16(Ah[ks].v, bl, acc[n], 0, 0, 0);
                acc[n] = __builtin_amdgcn_mfma_f32_16x16x32_bf16(Al[ks].v, bh, acc[n], 0, 0, 0);
            }
        }

        // ---- gates -> LDS tile [16][42] (D row=(lane>>4)*4+r = timestep) ----
#pragma unroll
        for (int n = 0; n < 3; ++n) {
            if (n == 2 && jj >= 8) continue;               // cols 40..47 are padding
#pragma unroll
            for (int r = 0; r < 4; ++r)
                gbuf[((lane >> 4) * 4 + r) * 42 + n * 16 + jj] = acc[n][r];
        }
        // ---- pre-read this tile's gates for lane's gate column pj, sA-folded ----
        float gv[16];
#pragma unroll
        for (int tt = 0; tt < 16; ++tt) gv[tt] = gbuf[tt * 42 + pj] * sA;

        // ---- recurrence ----
#pragma unroll
        for (int tt = 0; tt < 16; ++tt) {
            if (t0 + tt < Tlen) {
                float acs = gv[tt];                        // already sA-scaled
#pragma unroll
                for (int k = 0; k < Hs; ++k) acs = fmaf(hs[k], wcs[k], acs);
                float e  = __expf(acs);                    // exp(sA * pre_act)
                float sg = __builtin_amdgcn_rcpf(1.0f + e);
                float act = fmaf(sg, sM, sC);              // sigmoid(i,f,o) / tanh(g)
                int ai = __float_as_int(act);
                float a1d = __int_as_float(__builtin_amdgcn_mov_dpp(ai, 0xB1, 0xF, 0xF, true));
                float a2d = __int_as_float(__builtin_amdgcn_mov_dpp(ai, 0x4E, 0xF, 0xF, true));
                float a3d = __int_as_float(__builtin_amdgcn_mov_dpp(ai, 0x1B, 0xF, 0xF, true));
                cc = fmaf(a1d, cc, act * a2d);             // c = f*c + i*g (valid ty==0)
                float e2 = __expf(-2.0f * cc);
                float th = fmaf(2.0f, __builtin_amdgcn_rcpf(1.0f + e2), -1.0f);  // tanh(c)
                float hn = a3d * th;                       // h = o * tanh(c)
#pragma unroll
                for (int k = 0; k < Hs; ++k)
                    hs[k] = __int_as_float(__builtin_amdgcn_readlane(__float_as_int(hn), 4 * k));
            }
        }
    }

    if (lane == 0) {
        float o = lin_b[0];
#pragma unroll
        for (int k = 0; k < Hs; ++k) o = fmaf(hs[k], lin_w[k], o);
        out[b] = o;
    }
}

extern "C" void kernel_launch(void* const* d_in, const int* in_sizes, int n_in,
                              void* d_out, int out_size, void* d_ws, size_t ws_size,
                              hipStream_t stream) {
    const float* x = (const float*)d_in[0];
    float* w   = (float*)d_ws;
    float* out = (float*)d_out;

    prep_kernel<<<20, 256, 0, stream>>>(
        (const float*)d_in[1], (const float*)d_in[2], (const float*)d_in[3],
        (const float*)d_in[4], (const float*)d_in[5], (const float*)d_in[6],
        (const float*)d_in[7], (const float*)d_in[8], (const float*)d_in[9], w);

    fused_kernel<<<Bsz, 64, 0, stream>>>(
        x, w, (const float*)d_in[10], (const float*)d_in[11], out);
}